// Round 11
// baseline (214.382 us; speedup 1.0000x reference)
//
#include <hip/hip_runtime.h>

// ---------------------------------------------------------------------------
// QuantumQKGenerator, fully fused (R14): out[b] = expectations of
// S = QFT * U_circuit * normalize(x[b]).
//
// R13 post-mortem: LDS 17KB + VGPR 84 (6 waves/SIMD allowed) yet occupancy
// STUCK at 29% and dur at 107us -- identical to R7/R10.  Three TLP levers
// (launch-bounds x3, wave split, LDS halving) all null; VALUBusy pinned at
// ~64% = per-wave dependency stalls.  R14 buys ILP instead:
//
//   TWO ROWS PER WAVE (c[2][16], fully unrolled -> registers).  All
//   coefficient math (gate selects, twiddle rotations, sincos bases, LDS
//   addressing) is row-independent and computed ONCE; only the butterfly
//   FMA/shfl stream doubles.  Every dependent chain gets an independent
//   twin -> fills the 36% idle issue slots.  VGPR ~130-160 (free allocator,
//   never spilled), 3 waves/SIMD, LDS 32KB (not a cap at 3-4 blocks/CU).
// ---------------------------------------------------------------------------

typedef _Float16 half2_t __attribute__((ext_vector_type(2)));

__device__ __forceinline__ unsigned pk16(float a, float b) {
    half2_t h; h[0] = (_Float16)a; h[1] = (_Float16)b;    // RNE v_cvt_f16_f32
    return __builtin_bit_cast(unsigned, h);
}
__device__ __forceinline__ float2 up16(unsigned u) {
    half2_t h = __builtin_bit_cast(half2_t, u);
    return make_float2((float)h[0], (float)h[1]);
}

// 6-stage full-wave butterfly sum (all 64 lanes end with the total).
__device__ __forceinline__ float wred(float v) {
    v += __shfl_xor(v, 1);
    v += __shfl_xor(v, 2);
    v += __shfl_xor(v, 4);
    v += __shfl_xor(v, 8);
    v += __shfl_xor(v, 16);
    v += __shfl_xor(v, 32);
    return v;
}

// CNOT-ring + bit-reversal permutation (R5/R7-verified), GF(2)-linear.
__device__ __forceinline__ int cnotrev(int k) {
    int m = (int)(__brev((unsigned)k) >> 22);
    #pragma unroll
    for (int q = 9; q >= 0; --q) {
        const int pc = (q == 9) ? 0 : 9 - q;
        const int pt = (q == 9) ? 9 : 8 - q;
        m ^= ((m >> pc) & 1) << pt;
    }
    return m;
}

__global__ __launch_bounds__(256) void fused_kernel(const float* __restrict__ w,
                                                    const float* __restrict__ x,
                                                    float* __restrict__ out)
{
    __shared__ float uu[10][8];                    // combined Mz*My*Mx per wire
    __shared__ float ryc[10], rys[10];             // layer-3 RY coefficients
    __shared__ __align__(16) unsigned scr[4][2048];// per-wave fp16 scratch, 2 rows
    const int tid = threadIdx.x;
    const int wv = tid >> 6, l = tid & 63;
    const int row0 = blockIdx.x * 8 + wv * 2;
    unsigned* bw = scr[wv];                        // row r at unsigned-offset r*1024

    // ---- per-block setup: combined single-qubit unitaries (uniform) ----
    if (tid < 10) {
        float t0 = w[tid*4 + 0] * 0.5f, t1 = w[tid*4 + 1] * 0.5f;
        float t2 = w[tid*4 + 2] * 0.5f, t3 = w[tid*4 + 3] * 0.5f;
        float s0, c0, s1, c1, s2, c2, s3, c3;
        __sincosf(t0, &s0, &c0);
        __sincosf(t1, &s1, &c1);
        __sincosf(t2, &s2, &c2);
        __sincosf(t3, &s3, &c3);
        // M = Mz*My*Mx (RX applied first) -- R7-verified.
        uu[tid][0] =  c2*c1*c0 + s2*s1*s0;     // u00r
        uu[tid][1] =  c2*s1*s0 - s2*c1*c0;     // u00i
        uu[tid][2] = -(c2*s1*c0 + s2*c1*s0);   // u01r
        uu[tid][3] =  s2*s1*c0 - c2*c1*s0;     // u01i
        uu[tid][4] =  c2*s1*c0 + s2*c1*s0;     // u10r
        uu[tid][5] =  s2*s1*c0 - c2*c1*s0;     // u10i
        uu[tid][6] =  c2*c1*c0 + s2*s1*s0;     // u11r =  u00r
        uu[tid][7] =  s2*c1*c0 - c2*s1*s0;     // u11i = -u00i
        ryc[tid] = c3;
        rys[tid] = s3;
    }
    __syncthreads();

    // ---- load two rows, normalize each (1/||x|| * 1/32 in one scale) ----
    float2 c[2][16];
    #pragma unroll
    for (int r = 0; r < 2; ++r) {
        const float* xr = x + (size_t)(row0 + r) * 1024 + l * 16;
        float4 v0 = ((const float4*)xr)[0];
        float4 v1 = ((const float4*)xr)[1];
        float4 v2 = ((const float4*)xr)[2];
        float4 v3 = ((const float4*)xr)[3];
        float ss = v0.x*v0.x + v0.y*v0.y + v0.z*v0.z + v0.w*v0.w
                 + v1.x*v1.x + v1.y*v1.y + v1.z*v1.z + v1.w*v1.w
                 + v2.x*v2.x + v2.y*v2.y + v2.z*v2.z + v2.w*v2.w
                 + v3.x*v3.x + v3.y*v3.y + v3.z*v3.z + v3.w*v3.w;
        ss = wred(ss);
        const float scale = 0.03125f / fmaxf(sqrtf(ss), 1e-8f);
        c[r][0]  = make_float2(v0.x*scale, 0.f); c[r][1]  = make_float2(v0.y*scale, 0.f);
        c[r][2]  = make_float2(v0.z*scale, 0.f); c[r][3]  = make_float2(v0.w*scale, 0.f);
        c[r][4]  = make_float2(v1.x*scale, 0.f); c[r][5]  = make_float2(v1.y*scale, 0.f);
        c[r][6]  = make_float2(v1.z*scale, 0.f); c[r][7]  = make_float2(v1.w*scale, 0.f);
        c[r][8]  = make_float2(v2.x*scale, 0.f); c[r][9]  = make_float2(v2.y*scale, 0.f);
        c[r][10] = make_float2(v2.z*scale, 0.f); c[r][11] = make_float2(v2.w*scale, 0.f);
        c[r][12] = make_float2(v3.x*scale, 0.f); c[r][13] = make_float2(v3.y*scale, 0.f);
        c[r][14] = make_float2(v3.z*scale, 0.f); c[r][15] = make_float2(v3.w*scale, 0.f);
    }

    // ---- combined RX/RY/RZ layers: bit p <-> wire 9-p (R7-verified) ----
    #pragma unroll
    for (int p = 0; p < 4; ++p) {
        const float* U = uu[9 - p];
        const float u00r = U[0], u00i = U[1], u01r = U[2], u01i = U[3];
        const float u10r = U[4], u10i = U[5], u11r = U[6], u11i = U[7];
        const int m = 1 << p;
        #pragma unroll
        for (int i = 0; i < 16; ++i) {
            if (i & m) continue;
            const int j = i | m;
            #pragma unroll
            for (int r = 0; r < 2; ++r) {
                const float ar = c[r][i].x, ai = c[r][i].y;
                const float br = c[r][j].x, bi = c[r][j].y;
                c[r][i].x = u00r*ar - u00i*ai + u01r*br - u01i*bi;
                c[r][i].y = u00r*ai + u00i*ar + u01r*bi + u01i*br;
                c[r][j].x = u10r*ar - u10i*ai + u11r*br - u11i*bi;
                c[r][j].y = u10r*ai + u10i*ar + u11r*bi + u11i*br;
            }
        }
    }
    #pragma unroll
    for (int e = 0; e < 6; ++e) {
        const float* U = uu[5 - e];
        const int mybit = (l >> e) & 1;
        const float car = mybit ? U[6] : U[0];
        const float cai = mybit ? U[7] : U[1];
        const float cbr = mybit ? U[4] : U[2];
        const float cbi = mybit ? U[5] : U[3];
        #pragma unroll
        for (int i = 0; i < 16; ++i) {
            #pragma unroll
            for (int r = 0; r < 2; ++r) {
                const float fr = __shfl_xor(c[r][i].x, 1 << e);
                const float fi = __shfl_xor(c[r][i].y, 1 << e);
                const float ar = c[r][i].x, ai = c[r][i].y;
                c[r][i].x = car*ar - cai*ai + cbr*fr - cbi*fi;
                c[r][i].y = car*ai + cai*ar + cbr*fi + cbi*fr;
            }
        }
    }

    // ---- CNOT ring + bit-reversal: wave-local fp16 LDS gather (both rows) ----
    #pragma unroll
    for (int r = 0; r < 2; ++r) {
        #pragma unroll
        for (int j = 0; j < 8; ++j) {
            const int su = r*512 + l*8 + (j ^ (l & 7));
            uint2 pv;
            pv.x = pk16(c[r][2*j].x,     c[r][2*j].y);
            pv.y = pk16(c[r][2*j + 1].x, c[r][2*j + 1].y);
            ((uint2*)bw)[su] = pv;
        }
    }
    const int mb = cnotrev(l << 4);
    #pragma unroll
    for (int i = 0; i < 16; ++i) {
        const int m = mb ^ cnotrev(i);          // cnotrev(i) constant-folds
        const int lm = m >> 4, um = (m >> 1) & 7, lo = m & 1;
        const int base = (lm*8 + (um ^ (lm & 7)))*2 + lo;
        c[0][i] = up16(bw[base]);
        c[1][i] = up16(bw[1024 + base]);
    }

    // ---- layer-3 RY on REVERSED bits: bit p <-> wire p (R7-verified) ----
    #pragma unroll
    for (int p = 0; p < 4; ++p) {
        const float cc = ryc[p], sv = rys[p];
        const int m = 1 << p;
        #pragma unroll
        for (int i = 0; i < 16; ++i) {
            if (i & m) continue;
            const int j = i | m;
            #pragma unroll
            for (int r = 0; r < 2; ++r) {
                const float ar = c[r][i].x, ai = c[r][i].y;
                const float br = c[r][j].x, bi = c[r][j].y;
                c[r][i].x = cc*ar - sv*br;  c[r][i].y = cc*ai - sv*bi;
                c[r][j].x = sv*ar + cc*br;  c[r][j].y = sv*ai + cc*bi;
            }
        }
    }
    #pragma unroll
    for (int e = 0; e < 6; ++e) {
        const float cc = ryc[4 + e], sv = rys[4 + e];
        const int mybit = (l >> e) & 1;
        const float sel = mybit ? sv : -sv;
        #pragma unroll
        for (int i = 0; i < 16; ++i) {
            #pragma unroll
            for (int r = 0; r < 2; ++r) {
                const float fr = __shfl_xor(c[r][i].x, 1 << e);
                const float fi = __shfl_xor(c[r][i].y, 1 << e);
                c[r][i].x = cc*c[r][i].x + sel*fr;
                c[r][i].y = cc*c[r][i].y + sel*fi;
            }
        }
    }

    // ---- 1024-pt DIT FFT (bit-reversed input, positive twiddles) ----
    // intra-lane stages 1..4: compile-time pi/8-step twiddle tables
    {
        const float TC8[8] = { 1.f,  0.92387953f,  0.70710678f,  0.38268343f,
                               0.f, -0.38268343f, -0.70710678f, -0.92387953f };
        const float TS8[8] = { 0.f,  0.38268343f,  0.70710678f,  0.92387953f,
                               1.f,  0.92387953f,  0.70710678f,  0.38268343f };
        #pragma unroll
        for (int st = 1; st <= 4; ++st) {
            const int hf = 1 << (st - 1);
            #pragma unroll
            for (int i = 0; i < 16; ++i) {
                if (i & hf) continue;
                const int j = i | hf;
                const int tix = (i & (hf - 1)) << (4 - st);
                const float cwv = TC8[tix], swv = TS8[tix];
                #pragma unroll
                for (int r = 0; r < 2; ++r) {
                    const float tr = cwv*c[r][j].x - swv*c[r][j].y;
                    const float ti = cwv*c[r][j].y + swv*c[r][j].x;
                    const float ur = c[r][i].x, ui = c[r][i].y;
                    c[r][i].x = ur + tr; c[r][i].y = ui + ti;
                    c[r][j].x = ur - tr; c[r][j].y = ui - ti;
                }
            }
        }
    }
    // cross-lane stages 5..10: w(i) = w_base * W^i, W^i compile-time;
    // twiddle rotation SHARED between rows; premultiply-exchange butterfly.
    {
        const float CT[6][16] = {
          { 1.f,0.98078528f,0.92387953f,0.83146961f,0.70710678f,0.55557023f,0.38268343f,0.19509032f,
            0.f,-0.19509032f,-0.38268343f,-0.55557023f,-0.70710678f,-0.83146961f,-0.92387953f,-0.98078528f },
          { 1.f,0.99518473f,0.98078528f,0.95694034f,0.92387953f,0.88192126f,0.83146961f,0.77301045f,
            0.70710678f,0.63439328f,0.55557023f,0.47139674f,0.38268343f,0.29028468f,0.19509032f,0.09801714f },
          { 1.f,0.99879546f,0.99518473f,0.98917651f,0.98078528f,0.97003125f,0.95694034f,0.94154407f,
            0.92387953f,0.90398929f,0.88192126f,0.85772861f,0.83146961f,0.80320753f,0.77301045f,0.74095113f },
          { 1.f,0.99969882f,0.99879546f,0.99729046f,0.99518473f,0.99247953f,0.98917651f,0.98527764f,
            0.98078528f,0.97570213f,0.97003125f,0.96377607f,0.95694034f,0.94952818f,0.94154407f,0.93299280f },
          { 1.f,0.99992470f,0.99969882f,0.99932238f,0.99879546f,0.99811811f,0.99729046f,0.99631261f,
            0.99518473f,0.99390697f,0.99247953f,0.99090264f,0.98917651f,0.98730142f,0.98527764f,0.98310549f },
          { 1.f,0.99998118f,0.99992470f,0.99983058f,0.99969882f,0.99952942f,0.99932238f,0.99907773f,
            0.99879546f,0.99847559f,0.99811811f,0.99772307f,0.99729046f,0.99682030f,0.99631261f,0.99576742f } };
        const float ST[6][16] = {
          { 0.f,0.19509032f,0.38268343f,0.55557023f,0.70710678f,0.83146961f,0.92387953f,0.98078528f,
            1.f,0.98078528f,0.92387953f,0.83146961f,0.70710678f,0.55557023f,0.38268343f,0.19509032f },
          { 0.f,0.09801714f,0.19509032f,0.29028468f,0.38268343f,0.47139674f,0.55557023f,0.63439328f,
            0.70710678f,0.77301045f,0.83146961f,0.88192126f,0.92387953f,0.95694034f,0.98078528f,0.99518473f },
          { 0.f,0.04906767f,0.09801714f,0.14673047f,0.19509032f,0.24298018f,0.29028468f,0.33688985f,
            0.38268343f,0.42755509f,0.47139674f,0.51410274f,0.55557023f,0.59569930f,0.63439328f,0.67155895f },
          { 0.f,0.02454123f,0.04906767f,0.07356456f,0.09801714f,0.12241068f,0.14673047f,0.17096189f,
            0.19509032f,0.21910124f,0.24298018f,0.26671276f,0.29028468f,0.31368174f,0.33688985f,0.35989504f },
          { 0.f,0.01227154f,0.02454123f,0.03680722f,0.04906767f,0.06132074f,0.07356456f,0.08579731f,
            0.09801714f,0.11022221f,0.12241068f,0.13458071f,0.14673047f,0.15885814f,0.17096189f,0.18303989f },
          { 0.f,0.00613588f,0.01227154f,0.01840673f,0.02454123f,0.03067480f,0.03680722f,0.04293826f,
            0.04906767f,0.05519524f,0.06132074f,0.06744392f,0.07356456f,0.07968244f,0.08579731f,0.09190896f } };
        #pragma unroll
        for (int e2 = 0; e2 < 6; ++e2) {
            const int st = 5 + e2;
            const float astep = 6.28318530717958647f / (float)(1 << st);
            const int mybit = (l >> e2) & 1;
            const float sel = mybit ? -1.f : 1.f;
            float cb, sb;
            __sincosf(astep * 16.0f * (float)(l & ((1 << e2) - 1)), &sb, &cb);
            #pragma unroll
            for (int i = 0; i < 16; ++i) {
                const float cw = cb*CT[e2][i] - sb*ST[e2][i];   // wb * W^i (shared)
                const float sw = sb*CT[e2][i] + cb*ST[e2][i];
                #pragma unroll
                for (int r = 0; r < 2; ++r) {
                    const float pr = cw*c[r][i].x - sw*c[r][i].y;   // w * own
                    const float pi = cw*c[r][i].y + sw*c[r][i].x;
                    const float vr = mybit ? pr : c[r][i].x;        // b-lane sends w*b
                    const float vi = mybit ? pi : c[r][i].y;
                    const float fr = __shfl_xor(vr, 1 << e2);
                    const float fi = __shfl_xor(vi, 1 << e2);
                    c[r][i].x = fmaf(sel, vr, fr);                  // a: a+w*b, b: a-w*b
                    c[r][i].y = fmaf(sel, vi, fi);
                }
            }
        }
    }

    // ---- expectations (R7-verified structure; fp16 staged partners) ----
    #pragma unroll
    for (int r = 0; r < 2; ++r) {
        #pragma unroll
        for (int j = 0; j < 8; ++j) {
            const int su = r*512 + l*8 + (j ^ (l & 7));
            uint2 pv;
            pv.x = pk16(c[r][2*j].x,     c[r][2*j].y);
            pv.y = pk16(c[r][2*j + 1].x, c[r][2*j + 1].y);
            ((uint2*)bw)[su] = pv;
        }
    }

    float P2s[2] = {0.f, 0.f};
    #pragma unroll
    for (int i = 0; i < 16; ++i) {
        P2s[0] += c[0][i].x*c[0][i].x + c[0][i].y*c[0][i].y;
        P2s[1] += c[1][i].x*c[1][i].x + c[1][i].y*c[1][i].y;
    }

    float outv[2] = {0.f, 0.f};   // lane o ends up holding out[row][o]

    // intra-lane qubits: k-bit p = 0..3 -> q = 9-p
    #pragma unroll
    for (int p = 0; p < 4; ++p) {
        const int m = 1 << p;
        const int q = 9 - p;
        #pragma unroll
        for (int r = 0; r < 2; ++r) {
            float rr = 0.f, ii = 0.f, zz = 0.f;
            #pragma unroll
            for (int i = 0; i < 16; ++i) {
                if (i & m) continue;
                const int j = i | m;
                rr += c[r][i].x*c[r][j].x + c[r][i].y*c[r][j].y;
                ii += c[r][i].x*c[r][j].y - c[r][i].y*c[r][j].x;
                zz += (c[r][i].x*c[r][i].x + c[r][i].y*c[r][i].y)
                    - (c[r][j].x*c[r][j].x + c[r][j].y*c[r][j].y);
            }
            rr = wred(rr);
            ii = wred(ii);
            zz = wred(zz);
            outv[r] = (l == q)      ? 2.f*rr : outv[r];
            outv[r] = (l == 10 + q) ? 2.f*ii : outv[r];
            outv[r] = (l == 20 + q) ? zz     : outv[r];
        }
    }

    // cross-lane qubits: lane-bit e (k-bit 4+e) -> q = 5-e
    #pragma unroll
    for (int e = 0; e < 6; ++e) {
        const int q = 5 - e;
        const int part = l ^ (1 << e);
        const int mybit = (l >> e) & 1;
        const float sgn = mybit ? -1.f : 1.f;
        const int j0 = mybit ? 4 : 0;   // my half of the pair's units (LDS addr only)
        #pragma unroll
        for (int r = 0; r < 2; ++r) {
            float rr = 0.f, ii = 0.f;
            #pragma unroll
            for (int j = 0; j < 4; ++j) {
                const int su = r*512 + part*8 + ((j0 + j) ^ (part & 7));
                const uint2 d = ((const uint2*)bw)[su];
                const float2 f01 = up16(d.x);
                const float2 f23 = up16(d.y);
                const float2 a0 = c[r][2*j],     a1 = c[r][2*j + 1];
                const float2 b0 = c[r][2*j + 8], b1 = c[r][2*j + 9];
                const float m0x = mybit ? b0.x : a0.x;
                const float m0y = mybit ? b0.y : a0.y;
                const float m1x = mybit ? b1.x : a1.x;
                const float m1y = mybit ? b1.y : a1.y;
                rr += m0x*f01.x + m0y*f01.y;
                ii += m0x*f01.y - m0y*f01.x;
                rr += m1x*f23.x + m1y*f23.y;
                ii += m1x*f23.y - m1y*f23.x;
            }
            const float rr_s = wred(rr);
            const float ii_s = wred(sgn * ii);
            const float zz_s = wred(sgn * P2s[r]);
            outv[r] = (l == q)      ? 2.f*rr_s : outv[r];
            outv[r] = (l == 10 + q) ? 2.f*ii_s : outv[r];
            outv[r] = (l == 20 + q) ? zz_s     : outv[r];
        }
    }

    if (l < 30) {
        out[(size_t)(row0 + 0) * 30 + l] = outv[0];
        out[(size_t)(row0 + 1) * 30 + l] = outv[1];
    }
}

// ---------------------------------------------------------------------------
extern "C" void kernel_launch(void* const* d_in, const int* in_sizes, int n_in,
                              void* d_out, int out_size, void* d_ws, size_t ws_size,
                              hipStream_t stream) {
    const float* x = (const float*)d_in[0];   // [8192][1024]
    const float* w = (const float*)d_in[1];   // [10][4]
    float* out = (float*)d_out;               // [8192][30]
    (void)d_ws; (void)ws_size;                // workspace not needed

    fused_kernel<<<1024, 256, 0, stream>>>(w, x, out);
}

// Round 12
// 145.786 us; speedup vs baseline: 1.4705x; 1.4705x over previous
//
#include <hip/hip_runtime.h>

// ---------------------------------------------------------------------------
// QuantumQKGenerator, fully fused (R15): out[b] = expectations of
// S = QFT * U_circuit * normalize(x[b]).  One wave per row, amps in regs.
//
// R14 post-mortem: 2-row ILP lost (VGPR 148 -> occupancy 11%, 165us).
// Reverted to R13 (104.7us).  Occupancy levers exhausted (launch-bounds x3,
// wave-split, fp16-LDS, 2-row ILP: all null/negative; occupancy pinned 29%).
// R15 targets the measured stall directly: ~756 __shfl_xor per wave lower
// to addr-VALU + ds_bpermute (LDS pipe, ~30cy).  Replace with fixed-pattern
// primitives where they exist:
//   xor 1,2  -> DPP quad_perm (v_mov_b32_dpp 0xB1/0x4E): pure VALU, 0 addr
//   xor 4,8,16 -> ds_swizzle compile-time pattern ((m<<10)|0x1F): 0 addr
//   xor 32   -> __shfl_xor unchanged (swizzle is 32-lane-limited)
// ~630 fewer VALU ops, 252 fewer LDS-pipe ops, shorter dep chains.
// All call sites are uniform control flow (DPP/swizzle requirement).
// ---------------------------------------------------------------------------

typedef _Float16 half2_t __attribute__((ext_vector_type(2)));

__device__ __forceinline__ unsigned pk16(float a, float b) {
    half2_t h; h[0] = (_Float16)a; h[1] = (_Float16)b;    // RNE v_cvt_f16_f32
    return __builtin_bit_cast(unsigned, h);
}
__device__ __forceinline__ float2 up16(unsigned u) {
    half2_t h = __builtin_bit_cast(half2_t, u);
    return make_float2((float)h[0], (float)h[1]);
}

// cross-lane XOR exchange; e is compile-time after full unroll, so each
// branch folds and the builtins see literal args.
__device__ __forceinline__ float lxor(float v, int e) {
    if (e == 0)        // quad_perm [1,0,3,2]
        return __builtin_bit_cast(float, __builtin_amdgcn_mov_dpp(
            __builtin_bit_cast(int, v), 0xB1, 0xF, 0xF, true));
    else if (e == 1)   // quad_perm [2,3,0,1]
        return __builtin_bit_cast(float, __builtin_amdgcn_mov_dpp(
            __builtin_bit_cast(int, v), 0x4E, 0xF, 0xF, true));
    else if (e == 2)   // ds_swizzle bit-mode xor4
        return __builtin_bit_cast(float, __builtin_amdgcn_ds_swizzle(
            __builtin_bit_cast(int, v), (4 << 10) | 0x1F));
    else if (e == 3)   // xor8
        return __builtin_bit_cast(float, __builtin_amdgcn_ds_swizzle(
            __builtin_bit_cast(int, v), (8 << 10) | 0x1F));
    else if (e == 4)   // xor16
        return __builtin_bit_cast(float, __builtin_amdgcn_ds_swizzle(
            __builtin_bit_cast(int, v), (16 << 10) | 0x1F));
    else               // xor32: crosses the 32-lane swizzle boundary
        return __shfl_xor(v, 32);
}

// 6-stage full-wave butterfly sum (all 64 lanes end with the total).
__device__ __forceinline__ float wred(float v) {
    v += lxor(v, 0);
    v += lxor(v, 1);
    v += lxor(v, 2);
    v += lxor(v, 3);
    v += lxor(v, 4);
    v += lxor(v, 5);
    return v;
}

// CNOT-ring + bit-reversal permutation (R5/R7-verified), GF(2)-linear.
__device__ __forceinline__ int cnotrev(int k) {
    int m = (int)(__brev((unsigned)k) >> 22);
    #pragma unroll
    for (int q = 9; q >= 0; --q) {
        const int pc = (q == 9) ? 0 : 9 - q;
        const int pt = (q == 9) ? 9 : 8 - q;
        m ^= ((m >> pc) & 1) << pt;
    }
    return m;
}

__global__ __launch_bounds__(256) void fused_kernel(const float* __restrict__ w,
                                                    const float* __restrict__ x,
                                                    float* __restrict__ out)
{
    __shared__ float uu[10][8];                    // combined Mz*My*Mx per wire
    __shared__ float ryc[10], rys[10];             // layer-3 RY coefficients
    __shared__ __align__(16) unsigned scr[4][1024];// per-wave fp16 scratch (4KB)
    const int tid = threadIdx.x;
    const int wv = tid >> 6, l = tid & 63;
    const int row = blockIdx.x * 4 + wv;
    unsigned* bw = scr[wv];

    // ---- per-block setup: combined single-qubit unitaries (uniform) ----
    if (tid < 10) {
        float t0 = w[tid*4 + 0] * 0.5f, t1 = w[tid*4 + 1] * 0.5f;
        float t2 = w[tid*4 + 2] * 0.5f, t3 = w[tid*4 + 3] * 0.5f;
        float s0, c0, s1, c1, s2, c2, s3, c3;
        __sincosf(t0, &s0, &c0);
        __sincosf(t1, &s1, &c1);
        __sincosf(t2, &s2, &c2);
        __sincosf(t3, &s3, &c3);
        // M = Mz*My*Mx (RX applied first) -- R7-verified.
        uu[tid][0] =  c2*c1*c0 + s2*s1*s0;     // u00r
        uu[tid][1] =  c2*s1*s0 - s2*c1*c0;     // u00i
        uu[tid][2] = -(c2*s1*c0 + s2*c1*s0);   // u01r
        uu[tid][3] =  s2*s1*c0 - c2*c1*s0;     // u01i
        uu[tid][4] =  c2*s1*c0 + s2*c1*s0;     // u10r
        uu[tid][5] =  s2*s1*c0 - c2*c1*s0;     // u10i
        uu[tid][6] =  c2*c1*c0 + s2*s1*s0;     // u11r =  u00r
        uu[tid][7] =  s2*c1*c0 - c2*s1*s0;     // u11i = -u00i
        ryc[tid] = c3;
        rys[tid] = s3;
    }
    __syncthreads();

    // ---- load row, normalize (1/||x|| * 1/32 folded into one scale) ----
    const float* xr = x + (size_t)row * 1024 + l * 16;
    float4 v0 = ((const float4*)xr)[0];
    float4 v1 = ((const float4*)xr)[1];
    float4 v2 = ((const float4*)xr)[2];
    float4 v3 = ((const float4*)xr)[3];
    float ss = v0.x*v0.x + v0.y*v0.y + v0.z*v0.z + v0.w*v0.w
             + v1.x*v1.x + v1.y*v1.y + v1.z*v1.z + v1.w*v1.w
             + v2.x*v2.x + v2.y*v2.y + v2.z*v2.z + v2.w*v2.w
             + v3.x*v3.x + v3.y*v3.y + v3.z*v3.z + v3.w*v3.w;
    ss = wred(ss);
    const float scale = 0.03125f / fmaxf(sqrtf(ss), 1e-8f);

    float2 c[16];
    c[0]  = make_float2(v0.x*scale, 0.f); c[1]  = make_float2(v0.y*scale, 0.f);
    c[2]  = make_float2(v0.z*scale, 0.f); c[3]  = make_float2(v0.w*scale, 0.f);
    c[4]  = make_float2(v1.x*scale, 0.f); c[5]  = make_float2(v1.y*scale, 0.f);
    c[6]  = make_float2(v1.z*scale, 0.f); c[7]  = make_float2(v1.w*scale, 0.f);
    c[8]  = make_float2(v2.x*scale, 0.f); c[9]  = make_float2(v2.y*scale, 0.f);
    c[10] = make_float2(v2.z*scale, 0.f); c[11] = make_float2(v2.w*scale, 0.f);
    c[12] = make_float2(v3.x*scale, 0.f); c[13] = make_float2(v3.y*scale, 0.f);
    c[14] = make_float2(v3.z*scale, 0.f); c[15] = make_float2(v3.w*scale, 0.f);

    // ---- combined RX/RY/RZ layers: bit p <-> wire 9-p (R7-verified) ----
    #pragma unroll
    for (int p = 0; p < 4; ++p) {
        const float* U = uu[9 - p];
        const float u00r = U[0], u00i = U[1], u01r = U[2], u01i = U[3];
        const float u10r = U[4], u10i = U[5], u11r = U[6], u11i = U[7];
        const int m = 1 << p;
        #pragma unroll
        for (int i = 0; i < 16; ++i) {
            if (i & m) continue;
            const int j = i | m;
            const float ar = c[i].x, ai = c[i].y, br = c[j].x, bi = c[j].y;
            c[i].x = u00r*ar - u00i*ai + u01r*br - u01i*bi;
            c[i].y = u00r*ai + u00i*ar + u01r*bi + u01i*br;
            c[j].x = u10r*ar - u10i*ai + u11r*br - u11i*bi;
            c[j].y = u10r*ai + u10i*ar + u11r*bi + u11i*br;
        }
    }
    #pragma unroll
    for (int e = 0; e < 6; ++e) {
        const float* U = uu[5 - e];
        const int mybit = (l >> e) & 1;
        const float car = mybit ? U[6] : U[0];
        const float cai = mybit ? U[7] : U[1];
        const float cbr = mybit ? U[4] : U[2];
        const float cbi = mybit ? U[5] : U[3];
        #pragma unroll
        for (int i = 0; i < 16; ++i) {
            const float fr = lxor(c[i].x, e);
            const float fi = lxor(c[i].y, e);
            const float ar = c[i].x, ai = c[i].y;
            c[i].x = car*ar - cai*ai + cbr*fr - cbi*fi;
            c[i].y = car*ai + cai*ar + cbr*fi + cbi*fr;
        }
    }

    // ---- CNOT ring + bit-reversal: wave-local fp16 LDS gather ----
    #pragma unroll
    for (int j = 0; j < 8; ++j) {
        const int su = l*8 + (j ^ (l & 7));
        uint2 pv;
        pv.x = pk16(c[2*j].x,     c[2*j].y);
        pv.y = pk16(c[2*j + 1].x, c[2*j + 1].y);
        ((uint2*)bw)[su] = pv;
    }
    const int mb = cnotrev(l << 4);
    #pragma unroll
    for (int i = 0; i < 16; ++i) {
        const int m = mb ^ cnotrev(i);          // cnotrev(i) constant-folds
        const int lm = m >> 4, um = (m >> 1) & 7, lo = m & 1;
        c[i] = up16(bw[(lm*8 + (um ^ (lm & 7)))*2 + lo]);
    }

    // ---- layer-3 RY on REVERSED bits: bit p <-> wire p (R7-verified) ----
    #pragma unroll
    for (int p = 0; p < 4; ++p) {
        const float cc = ryc[p], sv = rys[p];
        const int m = 1 << p;
        #pragma unroll
        for (int i = 0; i < 16; ++i) {
            if (i & m) continue;
            const int j = i | m;
            const float ar = c[i].x, ai = c[i].y, br = c[j].x, bi = c[j].y;
            c[i].x = cc*ar - sv*br;  c[i].y = cc*ai - sv*bi;
            c[j].x = sv*ar + cc*br;  c[j].y = sv*ai + cc*bi;
        }
    }
    #pragma unroll
    for (int e = 0; e < 6; ++e) {
        const float cc = ryc[4 + e], sv = rys[4 + e];
        const int mybit = (l >> e) & 1;
        const float sel = mybit ? sv : -sv;
        #pragma unroll
        for (int i = 0; i < 16; ++i) {
            const float fr = lxor(c[i].x, e);
            const float fi = lxor(c[i].y, e);
            c[i].x = cc*c[i].x + sel*fr;
            c[i].y = cc*c[i].y + sel*fi;
        }
    }

    // ---- 1024-pt DIT FFT (bit-reversed input, positive twiddles) ----
    // intra-lane stages 1..4: compile-time pi/8-step twiddle tables
    {
        const float TC8[8] = { 1.f,  0.92387953f,  0.70710678f,  0.38268343f,
                               0.f, -0.38268343f, -0.70710678f, -0.92387953f };
        const float TS8[8] = { 0.f,  0.38268343f,  0.70710678f,  0.92387953f,
                               1.f,  0.92387953f,  0.70710678f,  0.38268343f };
        #pragma unroll
        for (int st = 1; st <= 4; ++st) {
            const int hf = 1 << (st - 1);
            #pragma unroll
            for (int i = 0; i < 16; ++i) {
                if (i & hf) continue;
                const int j = i | hf;
                const int tix = (i & (hf - 1)) << (4 - st);
                const float cwv = TC8[tix], swv = TS8[tix];
                const float tr = cwv*c[j].x - swv*c[j].y;
                const float ti = cwv*c[j].y + swv*c[j].x;
                const float ur = c[i].x, ui = c[i].y;
                c[i].x = ur + tr; c[i].y = ui + ti;
                c[j].x = ur - tr; c[j].y = ui - ti;
            }
        }
    }
    // cross-lane stages 5..10 (lane-bit e2, st = 5+e2):
    //   w(i) = w_base * W^i, W^i compile-time; premultiply-exchange butterfly.
    {
        const float CT[6][16] = {
          { 1.f,0.98078528f,0.92387953f,0.83146961f,0.70710678f,0.55557023f,0.38268343f,0.19509032f,
            0.f,-0.19509032f,-0.38268343f,-0.55557023f,-0.70710678f,-0.83146961f,-0.92387953f,-0.98078528f },
          { 1.f,0.99518473f,0.98078528f,0.95694034f,0.92387953f,0.88192126f,0.83146961f,0.77301045f,
            0.70710678f,0.63439328f,0.55557023f,0.47139674f,0.38268343f,0.29028468f,0.19509032f,0.09801714f },
          { 1.f,0.99879546f,0.99518473f,0.98917651f,0.98078528f,0.97003125f,0.95694034f,0.94154407f,
            0.92387953f,0.90398929f,0.88192126f,0.85772861f,0.83146961f,0.80320753f,0.77301045f,0.74095113f },
          { 1.f,0.99969882f,0.99879546f,0.99729046f,0.99518473f,0.99247953f,0.98917651f,0.98527764f,
            0.98078528f,0.97570213f,0.97003125f,0.96377607f,0.95694034f,0.94952818f,0.94154407f,0.93299280f },
          { 1.f,0.99992470f,0.99969882f,0.99932238f,0.99879546f,0.99811811f,0.99729046f,0.99631261f,
            0.99518473f,0.99390697f,0.99247953f,0.99090264f,0.98917651f,0.98730142f,0.98527764f,0.98310549f },
          { 1.f,0.99998118f,0.99992470f,0.99983058f,0.99969882f,0.99952942f,0.99932238f,0.99907773f,
            0.99879546f,0.99847559f,0.99811811f,0.99772307f,0.99729046f,0.99682030f,0.99631261f,0.99576742f } };
        const float ST[6][16] = {
          { 0.f,0.19509032f,0.38268343f,0.55557023f,0.70710678f,0.83146961f,0.92387953f,0.98078528f,
            1.f,0.98078528f,0.92387953f,0.83146961f,0.70710678f,0.55557023f,0.38268343f,0.19509032f },
          { 0.f,0.09801714f,0.19509032f,0.29028468f,0.38268343f,0.47139674f,0.55557023f,0.63439328f,
            0.70710678f,0.77301045f,0.83146961f,0.88192126f,0.92387953f,0.95694034f,0.98078528f,0.99518473f },
          { 0.f,0.04906767f,0.09801714f,0.14673047f,0.19509032f,0.24298018f,0.29028468f,0.33688985f,
            0.38268343f,0.42755509f,0.47139674f,0.51410274f,0.55557023f,0.59569930f,0.63439328f,0.67155895f },
          { 0.f,0.02454123f,0.04906767f,0.07356456f,0.09801714f,0.12241068f,0.14673047f,0.17096189f,
            0.19509032f,0.21910124f,0.24298018f,0.26671276f,0.29028468f,0.31368174f,0.33688985f,0.35989504f },
          { 0.f,0.01227154f,0.02454123f,0.03680722f,0.04906767f,0.06132074f,0.07356456f,0.08579731f,
            0.09801714f,0.11022221f,0.12241068f,0.13458071f,0.14673047f,0.15885814f,0.17096189f,0.18303989f },
          { 0.f,0.00613588f,0.01227154f,0.01840673f,0.02454123f,0.03067480f,0.03680722f,0.04293826f,
            0.04906767f,0.05519524f,0.06132074f,0.06744392f,0.07356456f,0.07968244f,0.08579731f,0.09190896f } };
        #pragma unroll
        for (int e2 = 0; e2 < 6; ++e2) {
            const int st = 5 + e2;
            const float astep = 6.28318530717958647f / (float)(1 << st);
            const int mybit = (l >> e2) & 1;
            const float sel = mybit ? -1.f : 1.f;
            float cb, sb;
            __sincosf(astep * 16.0f * (float)(l & ((1 << e2) - 1)), &sb, &cb);
            #pragma unroll
            for (int i = 0; i < 16; ++i) {
                const float cw = cb*CT[e2][i] - sb*ST[e2][i];   // wb * W^i
                const float sw = sb*CT[e2][i] + cb*ST[e2][i];
                const float pr = cw*c[i].x - sw*c[i].y;         // w * own
                const float pi = cw*c[i].y + sw*c[i].x;
                const float vr = mybit ? pr : c[i].x;           // b-lane sends w*b
                const float vi = mybit ? pi : c[i].y;
                const float fr = lxor(vr, e2);
                const float fi = lxor(vi, e2);
                c[i].x = fmaf(sel, vr, fr);                     // a: a+w*b, b: a-w*b
                c[i].y = fmaf(sel, vi, fi);
            }
        }
    }

    // ---- expectations (R7-verified structure; fp16 staged partners) ----
    #pragma unroll
    for (int j = 0; j < 8; ++j) {
        const int su = l*8 + (j ^ (l & 7));
        uint2 pv;
        pv.x = pk16(c[2*j].x,     c[2*j].y);
        pv.y = pk16(c[2*j + 1].x, c[2*j + 1].y);
        ((uint2*)bw)[su] = pv;
    }

    float P2s = 0.f;
    #pragma unroll
    for (int i = 0; i < 16; ++i)
        P2s += c[i].x*c[i].x + c[i].y*c[i].y;

    float outv = 0.f;   // lane o ends up holding out[row][o]

    // intra-lane qubits: k-bit p = 0..3 -> q = 9-p
    #pragma unroll
    for (int p = 0; p < 4; ++p) {
        const int m = 1 << p;
        const int q = 9 - p;
        float rr = 0.f, ii = 0.f, zz = 0.f;
        #pragma unroll
        for (int i = 0; i < 16; ++i) {
            if (i & m) continue;
            const int j = i | m;
            rr += c[i].x*c[j].x + c[i].y*c[j].y;
            ii += c[i].x*c[j].y - c[i].y*c[j].x;
            zz += (c[i].x*c[i].x + c[i].y*c[i].y) - (c[j].x*c[j].x + c[j].y*c[j].y);
        }
        rr = wred(rr);
        ii = wred(ii);
        zz = wred(zz);
        outv = (l == q)      ? 2.f*rr : outv;
        outv = (l == 10 + q) ? 2.f*ii : outv;
        outv = (l == 20 + q) ? zz     : outv;
    }

    // cross-lane qubits: lane-bit e (k-bit 4+e) -> q = 5-e
    #pragma unroll
    for (int e = 0; e < 6; ++e) {
        const int q = 5 - e;
        const int part = l ^ (1 << e);
        const int mybit = (l >> e) & 1;
        const float sgn = mybit ? -1.f : 1.f;
        const int j0 = mybit ? 4 : 0;   // my half of the pair's units (LDS addr only)
        float rr = 0.f, ii = 0.f;
        #pragma unroll
        for (int j = 0; j < 4; ++j) {
            const int su = part*8 + ((j0 + j) ^ (part & 7));
            const uint2 d = ((const uint2*)bw)[su];
            const float2 f01 = up16(d.x);   // partner complex 0 (re, im)
            const float2 f23 = up16(d.y);   // partner complex 1 (re, im)
            const float2 a0 = c[2*j],     a1 = c[2*j + 1];
            const float2 b0 = c[2*j + 8], b1 = c[2*j + 9];
            const float m0x = mybit ? b0.x : a0.x;
            const float m0y = mybit ? b0.y : a0.y;
            const float m1x = mybit ? b1.x : a1.x;
            const float m1y = mybit ? b1.y : a1.y;
            rr += m0x*f01.x + m0y*f01.y;
            ii += m0x*f01.y - m0y*f01.x;
            rr += m1x*f23.x + m1y*f23.y;
            ii += m1x*f23.y - m1y*f23.x;
        }
        const float rr_s = wred(rr);
        const float ii_s = wred(sgn * ii);
        const float zz_s = wred(sgn * P2s);
        outv = (l == q)      ? 2.f*rr_s : outv;
        outv = (l == 10 + q) ? 2.f*ii_s : outv;
        outv = (l == 20 + q) ? zz_s     : outv;
    }

    if (l < 30)
        out[(size_t)row * 30 + l] = outv;
}

// ---------------------------------------------------------------------------
extern "C" void kernel_launch(void* const* d_in, const int* in_sizes, int n_in,
                              void* d_out, int out_size, void* d_ws, size_t ws_size,
                              hipStream_t stream) {
    const float* x = (const float*)d_in[0];   // [8192][1024]
    const float* w = (const float*)d_in[1];   // [10][4]
    float* out = (float*)d_out;               // [8192][30]
    (void)d_ws; (void)ws_size;                // workspace not needed

    fused_kernel<<<2048, 256, 0, stream>>>(w, x, out);
}

// Round 14
// 142.504 us; speedup vs baseline: 1.5044x; 1.0230x over previous
//
#include <hip/hip_runtime.h>

// ---------------------------------------------------------------------------
// QuantumQKGenerator, fully fused (R16 resubmit): out[b] = expectations of
// S = QFT * U_circuit * normalize(x[b]).  One wave per row, amps in regs.
//
// R13 bench was an infra failure ("container failed twice") -- no signal on
// the kernel.  Resubmitting unchanged for a clean run.
//
// R15 post-mortem: lxor (DPP quad_perm for xor1/2, ds_swizzle for xor4/8/16)
// WORKED: 104.7 -> 97us, VALUBusy 64 -> 73% (ds_bpermute addr+latency was
// the stall source).  VGPR 84->108, occupancy 29->20% -- net positive:
// this kernel wants ILP, not residency.
//
// R16, two surgical cuts from verified code:
//  1) expect cross-lane phase via direct lxor exchange (math verified in
//     R12's passed two-wave kernel): deletes 2nd fp16 staging + per-stage
//     LDS loads/cvt/selects.  Re is swap-symmetric (no select); Im folds
//     into sgn; both lanes compute each pair -> wred already 2x -> no 2*.
//  2) cnotrev gather staging back to fp32 float4 (R7's verified block):
//     bw now has a single user; fp16 mid-circuit round-trip removed ->
//     absmax margin back to ~4.9e-4.  LDS 17->33KB changes nothing (VGPR
//     108 already caps 4 waves/SIMD).
// ---------------------------------------------------------------------------

// cross-lane XOR exchange; e is compile-time after full unroll, so each
// branch folds and the builtins see literal args.
__device__ __forceinline__ float lxor(float v, int e) {
    if (e == 0)        // quad_perm [1,0,3,2]
        return __builtin_bit_cast(float, __builtin_amdgcn_mov_dpp(
            __builtin_bit_cast(int, v), 0xB1, 0xF, 0xF, true));
    else if (e == 1)   // quad_perm [2,3,0,1]
        return __builtin_bit_cast(float, __builtin_amdgcn_mov_dpp(
            __builtin_bit_cast(int, v), 0x4E, 0xF, 0xF, true));
    else if (e == 2)   // ds_swizzle bit-mode xor4
        return __builtin_bit_cast(float, __builtin_amdgcn_ds_swizzle(
            __builtin_bit_cast(int, v), (4 << 10) | 0x1F));
    else if (e == 3)   // xor8
        return __builtin_bit_cast(float, __builtin_amdgcn_ds_swizzle(
            __builtin_bit_cast(int, v), (8 << 10) | 0x1F));
    else if (e == 4)   // xor16
        return __builtin_bit_cast(float, __builtin_amdgcn_ds_swizzle(
            __builtin_bit_cast(int, v), (16 << 10) | 0x1F));
    else               // xor32: crosses the 32-lane swizzle boundary
        return __shfl_xor(v, 32);
}

// 6-stage full-wave butterfly sum (all 64 lanes end with the total).
__device__ __forceinline__ float wred(float v) {
    v += lxor(v, 0);
    v += lxor(v, 1);
    v += lxor(v, 2);
    v += lxor(v, 3);
    v += lxor(v, 4);
    v += lxor(v, 5);
    return v;
}

// CNOT-ring + bit-reversal permutation (R5/R7-verified), GF(2)-linear.
__device__ __forceinline__ int cnotrev(int k) {
    int m = (int)(__brev((unsigned)k) >> 22);
    #pragma unroll
    for (int q = 9; q >= 0; --q) {
        const int pc = (q == 9) ? 0 : 9 - q;
        const int pt = (q == 9) ? 9 : 8 - q;
        m ^= ((m >> pc) & 1) << pt;
    }
    return m;
}

__global__ __launch_bounds__(256) void fused_kernel(const float* __restrict__ w,
                                                    const float* __restrict__ x,
                                                    float* __restrict__ out)
{
    __shared__ float uu[10][8];                    // combined Mz*My*Mx per wire
    __shared__ float ryc[10], rys[10];             // layer-3 RY coefficients
    __shared__ __align__(16) float scr[4][2048];   // per-wave fp32 scratch (8KB)
    const int tid = threadIdx.x;
    const int wv = tid >> 6, l = tid & 63;
    const int row = blockIdx.x * 4 + wv;
    float* bw = scr[wv];

    // ---- per-block setup: combined single-qubit unitaries (uniform) ----
    if (tid < 10) {
        float t0 = w[tid*4 + 0] * 0.5f, t1 = w[tid*4 + 1] * 0.5f;
        float t2 = w[tid*4 + 2] * 0.5f, t3 = w[tid*4 + 3] * 0.5f;
        float s0, c0, s1, c1, s2, c2, s3, c3;
        __sincosf(t0, &s0, &c0);
        __sincosf(t1, &s1, &c1);
        __sincosf(t2, &s2, &c2);
        __sincosf(t3, &s3, &c3);
        // M = Mz*My*Mx (RX applied first) -- R7-verified.
        uu[tid][0] =  c2*c1*c0 + s2*s1*s0;     // u00r
        uu[tid][1] =  c2*s1*s0 - s2*c1*c0;     // u00i
        uu[tid][2] = -(c2*s1*c0 + s2*c1*s0);   // u01r
        uu[tid][3] =  s2*s1*c0 - c2*c1*s0;     // u01i
        uu[tid][4] =  c2*s1*c0 + s2*c1*s0;     // u10r
        uu[tid][5] =  s2*s1*c0 - c2*c1*s0;     // u10i
        uu[tid][6] =  c2*c1*c0 + s2*s1*s0;     // u11r =  u00r
        uu[tid][7] =  s2*c1*c0 - c2*s1*s0;     // u11i = -u00i
        ryc[tid] = c3;
        rys[tid] = s3;
    }
    __syncthreads();

    // ---- load row, normalize (1/||x|| * 1/32 folded into one scale) ----
    const float* xr = x + (size_t)row * 1024 + l * 16;
    float4 v0 = ((const float4*)xr)[0];
    float4 v1 = ((const float4*)xr)[1];
    float4 v2 = ((const float4*)xr)[2];
    float4 v3 = ((const float4*)xr)[3];
    float ss = v0.x*v0.x + v0.y*v0.y + v0.z*v0.z + v0.w*v0.w
             + v1.x*v1.x + v1.y*v1.y + v1.z*v1.z + v1.w*v1.w
             + v2.x*v2.x + v2.y*v2.y + v2.z*v2.z + v2.w*v2.w
             + v3.x*v3.x + v3.y*v3.y + v3.z*v3.z + v3.w*v3.w;
    ss = wred(ss);
    const float scale = 0.03125f / fmaxf(sqrtf(ss), 1e-8f);

    float2 c[16];
    c[0]  = make_float2(v0.x*scale, 0.f); c[1]  = make_float2(v0.y*scale, 0.f);
    c[2]  = make_float2(v0.z*scale, 0.f); c[3]  = make_float2(v0.w*scale, 0.f);
    c[4]  = make_float2(v1.x*scale, 0.f); c[5]  = make_float2(v1.y*scale, 0.f);
    c[6]  = make_float2(v1.z*scale, 0.f); c[7]  = make_float2(v1.w*scale, 0.f);
    c[8]  = make_float2(v2.x*scale, 0.f); c[9]  = make_float2(v2.y*scale, 0.f);
    c[10] = make_float2(v2.z*scale, 0.f); c[11] = make_float2(v2.w*scale, 0.f);
    c[12] = make_float2(v3.x*scale, 0.f); c[13] = make_float2(v3.y*scale, 0.f);
    c[14] = make_float2(v3.z*scale, 0.f); c[15] = make_float2(v3.w*scale, 0.f);

    // ---- combined RX/RY/RZ layers: bit p <-> wire 9-p (R7-verified) ----
    #pragma unroll
    for (int p = 0; p < 4; ++p) {
        const float* U = uu[9 - p];
        const float u00r = U[0], u00i = U[1], u01r = U[2], u01i = U[3];
        const float u10r = U[4], u10i = U[5], u11r = U[6], u11i = U[7];
        const int m = 1 << p;
        #pragma unroll
        for (int i = 0; i < 16; ++i) {
            if (i & m) continue;
            const int j = i | m;
            const float ar = c[i].x, ai = c[i].y, br = c[j].x, bi = c[j].y;
            c[i].x = u00r*ar - u00i*ai + u01r*br - u01i*bi;
            c[i].y = u00r*ai + u00i*ar + u01r*bi + u01i*br;
            c[j].x = u10r*ar - u10i*ai + u11r*br - u11i*bi;
            c[j].y = u10r*ai + u10i*ar + u11r*bi + u11i*br;
        }
    }
    #pragma unroll
    for (int e = 0; e < 6; ++e) {
        const float* U = uu[5 - e];
        const int mybit = (l >> e) & 1;
        const float car = mybit ? U[6] : U[0];
        const float cai = mybit ? U[7] : U[1];
        const float cbr = mybit ? U[4] : U[2];
        const float cbi = mybit ? U[5] : U[3];
        #pragma unroll
        for (int i = 0; i < 16; ++i) {
            const float fr = lxor(c[i].x, e);
            const float fi = lxor(c[i].y, e);
            const float ar = c[i].x, ai = c[i].y;
            c[i].x = car*ar - cai*ai + cbr*fr - cbi*fi;
            c[i].y = car*ai + cai*ar + cbr*fi + cbi*fr;
        }
    }

    // ---- CNOT ring + bit-reversal: wave-local fp32 LDS gather (R7) ----
    #pragma unroll
    for (int j = 0; j < 8; ++j) {
        const int su = l*8 + (j ^ (l & 7));
        ((float4*)bw)[su] = make_float4(c[2*j].x, c[2*j].y, c[2*j+1].x, c[2*j+1].y);
    }
    const int mb = cnotrev(l << 4);
    #pragma unroll
    for (int i = 0; i < 16; ++i) {
        const int m = mb ^ cnotrev(i);          // cnotrev(i) constant-folds
        const int lm = m >> 4, um = (m >> 1) & 7, lo = m & 1;
        const int su = lm*8 + (um ^ (lm & 7));
        c[i] = ((const float2*)bw)[su*2 + lo];
    }

    // ---- layer-3 RY on REVERSED bits: bit p <-> wire p (R7-verified) ----
    #pragma unroll
    for (int p = 0; p < 4; ++p) {
        const float cc = ryc[p], sv = rys[p];
        const int m = 1 << p;
        #pragma unroll
        for (int i = 0; i < 16; ++i) {
            if (i & m) continue;
            const int j = i | m;
            const float ar = c[i].x, ai = c[i].y, br = c[j].x, bi = c[j].y;
            c[i].x = cc*ar - sv*br;  c[i].y = cc*ai - sv*bi;
            c[j].x = sv*ar + cc*br;  c[j].y = sv*ai + cc*bi;
        }
    }
    #pragma unroll
    for (int e = 0; e < 6; ++e) {
        const float cc = ryc[4 + e], sv = rys[4 + e];
        const int mybit = (l >> e) & 1;
        const float sel = mybit ? sv : -sv;
        #pragma unroll
        for (int i = 0; i < 16; ++i) {
            const float fr = lxor(c[i].x, e);
            const float fi = lxor(c[i].y, e);
            c[i].x = cc*c[i].x + sel*fr;
            c[i].y = cc*c[i].y + sel*fi;
        }
    }

    // ---- 1024-pt DIT FFT (bit-reversed input, positive twiddles) ----
    // intra-lane stages 1..4: compile-time pi/8-step twiddle tables
    {
        const float TC8[8] = { 1.f,  0.92387953f,  0.70710678f,  0.38268343f,
                               0.f, -0.38268343f, -0.70710678f, -0.92387953f };
        const float TS8[8] = { 0.f,  0.38268343f,  0.70710678f,  0.92387953f,
                               1.f,  0.92387953f,  0.70710678f,  0.38268343f };
        #pragma unroll
        for (int st = 1; st <= 4; ++st) {
            const int hf = 1 << (st - 1);
            #pragma unroll
            for (int i = 0; i < 16; ++i) {
                if (i & hf) continue;
                const int j = i | hf;
                const int tix = (i & (hf - 1)) << (4 - st);
                const float cwv = TC8[tix], swv = TS8[tix];
                const float tr = cwv*c[j].x - swv*c[j].y;
                const float ti = cwv*c[j].y + swv*c[j].x;
                const float ur = c[i].x, ui = c[i].y;
                c[i].x = ur + tr; c[i].y = ui + ti;
                c[j].x = ur - tr; c[j].y = ui - ti;
            }
        }
    }
    // cross-lane stages 5..10 (lane-bit e2, st = 5+e2):
    //   w(i) = w_base * W^i, W^i compile-time; premultiply-exchange butterfly.
    {
        const float CT[6][16] = {
          { 1.f,0.98078528f,0.92387953f,0.83146961f,0.70710678f,0.55557023f,0.38268343f,0.19509032f,
            0.f,-0.19509032f,-0.38268343f,-0.55557023f,-0.70710678f,-0.83146961f,-0.92387953f,-0.98078528f },
          { 1.f,0.99518473f,0.98078528f,0.95694034f,0.92387953f,0.88192126f,0.83146961f,0.77301045f,
            0.70710678f,0.63439328f,0.55557023f,0.47139674f,0.38268343f,0.29028468f,0.19509032f,0.09801714f },
          { 1.f,0.99879546f,0.99518473f,0.98917651f,0.98078528f,0.97003125f,0.95694034f,0.94154407f,
            0.92387953f,0.90398929f,0.88192126f,0.85772861f,0.83146961f,0.80320753f,0.77301045f,0.74095113f },
          { 1.f,0.99969882f,0.99879546f,0.99729046f,0.99518473f,0.99247953f,0.98917651f,0.98527764f,
            0.98078528f,0.97570213f,0.97003125f,0.96377607f,0.95694034f,0.94952818f,0.94154407f,0.93299280f },
          { 1.f,0.99992470f,0.99969882f,0.99932238f,0.99879546f,0.99811811f,0.99729046f,0.99631261f,
            0.99518473f,0.99390697f,0.99247953f,0.99090264f,0.98917651f,0.98730142f,0.98527764f,0.98310549f },
          { 1.f,0.99998118f,0.99992470f,0.99983058f,0.99969882f,0.99952942f,0.99932238f,0.99907773f,
            0.99879546f,0.99847559f,0.99811811f,0.99772307f,0.99729046f,0.99682030f,0.99631261f,0.99576742f } };
        const float ST[6][16] = {
          { 0.f,0.19509032f,0.38268343f,0.55557023f,0.70710678f,0.83146961f,0.92387953f,0.98078528f,
            1.f,0.98078528f,0.92387953f,0.83146961f,0.70710678f,0.55557023f,0.38268343f,0.19509032f },
          { 0.f,0.09801714f,0.19509032f,0.29028468f,0.38268343f,0.47139674f,0.55557023f,0.63439328f,
            0.70710678f,0.77301045f,0.83146961f,0.88192126f,0.92387953f,0.95694034f,0.98078528f,0.99518473f },
          { 0.f,0.04906767f,0.09801714f,0.14673047f,0.19509032f,0.24298018f,0.29028468f,0.33688985f,
            0.38268343f,0.42755509f,0.47139674f,0.51410274f,0.55557023f,0.59569930f,0.63439328f,0.67155895f },
          { 0.f,0.02454123f,0.04906767f,0.07356456f,0.09801714f,0.12241068f,0.14673047f,0.17096189f,
            0.19509032f,0.21910124f,0.24298018f,0.26671276f,0.29028468f,0.31368174f,0.33688985f,0.35989504f },
          { 0.f,0.01227154f,0.02454123f,0.03680722f,0.04906767f,0.06132074f,0.07356456f,0.08579731f,
            0.09801714f,0.11022221f,0.12241068f,0.13458071f,0.14673047f,0.15885814f,0.17096189f,0.18303989f },
          { 0.f,0.00613588f,0.01227154f,0.01840673f,0.02454123f,0.03067480f,0.03680722f,0.04293826f,
            0.04906767f,0.05519524f,0.06132074f,0.06744392f,0.07356456f,0.07968244f,0.08579731f,0.09190896f } };
        #pragma unroll
        for (int e2 = 0; e2 < 6; ++e2) {
            const int st = 5 + e2;
            const float astep = 6.28318530717958647f / (float)(1 << st);
            const int mybit = (l >> e2) & 1;
            const float sel = mybit ? -1.f : 1.f;
            float cb, sb;
            __sincosf(astep * 16.0f * (float)(l & ((1 << e2) - 1)), &sb, &cb);
            #pragma unroll
            for (int i = 0; i < 16; ++i) {
                const float cw = cb*CT[e2][i] - sb*ST[e2][i];   // wb * W^i
                const float sw = sb*CT[e2][i] + cb*ST[e2][i];
                const float pr = cw*c[i].x - sw*c[i].y;         // w * own
                const float pi = cw*c[i].y + sw*c[i].x;
                const float vr = mybit ? pr : c[i].x;           // b-lane sends w*b
                const float vi = mybit ? pi : c[i].y;
                const float fr = lxor(vr, e2);
                const float fi = lxor(vi, e2);
                c[i].x = fmaf(sel, vr, fr);                     // a: a+w*b, b: a-w*b
                c[i].y = fmaf(sel, vi, fi);
            }
        }
    }

    // ---- expectations ----
    float P2s = 0.f;
    #pragma unroll
    for (int i = 0; i < 16; ++i)
        P2s += c[i].x*c[i].x + c[i].y*c[i].y;

    float outv = 0.f;   // lane o ends up holding out[row][o]

    // intra-lane qubits: k-bit p = 0..3 -> q = 9-p  (pairs counted once: 2x)
    #pragma unroll
    for (int p = 0; p < 4; ++p) {
        const int m = 1 << p;
        const int q = 9 - p;
        float rr = 0.f, ii = 0.f, zz = 0.f;
        #pragma unroll
        for (int i = 0; i < 16; ++i) {
            if (i & m) continue;
            const int j = i | m;
            rr += c[i].x*c[j].x + c[i].y*c[j].y;
            ii += c[i].x*c[j].y - c[i].y*c[j].x;
            zz += (c[i].x*c[i].x + c[i].y*c[i].y) - (c[j].x*c[j].x + c[j].y*c[j].y);
        }
        rr = wred(rr);
        ii = wred(ii);
        zz = wred(zz);
        outv = (l == q)      ? 2.f*rr : outv;
        outv = (l == 10 + q) ? 2.f*ii : outv;
        outv = (l == 20 + q) ? zz     : outv;
    }

    // cross-lane qubits: lane-bit e (k-bit 4+e) -> q = 5-e.
    // Direct lxor partner exchange (R12-verified math): BOTH lanes of a
    // pair compute it -> wred totals already 2x -> no 2* factor.
    // Re(conj(s0)s1) is swap-symmetric (no select); Im antisymmetric (sgn).
    #pragma unroll
    for (int e = 0; e < 6; ++e) {
        const int q = 5 - e;
        const int mybit = (l >> e) & 1;
        const float sgn = mybit ? -1.f : 1.f;
        float rr = 0.f, ii = 0.f;
        #pragma unroll
        for (int i = 0; i < 16; ++i) {
            const float fr = lxor(c[i].x, e);
            const float fi = lxor(c[i].y, e);
            rr += c[i].x*fr + c[i].y*fi;
            ii += c[i].x*fi - c[i].y*fr;
        }
        const float rr_s = wred(rr);
        const float ii_s = wred(sgn * ii);
        const float zz_s = wred(sgn * P2s);
        outv = (l == q)      ? rr_s : outv;   // already 2*Re
        outv = (l == 10 + q) ? ii_s : outv;   // already 2*Im
        outv = (l == 20 + q) ? zz_s : outv;
    }

    if (l < 30)
        out[(size_t)row * 30 + l] = outv;
}

// ---------------------------------------------------------------------------
extern "C" void kernel_launch(void* const* d_in, const int* in_sizes, int n_in,
                              void* d_out, int out_size, void* d_ws, size_t ws_size,
                              hipStream_t stream) {
    const float* x = (const float*)d_in[0];   // [8192][1024]
    const float* w = (const float*)d_in[1];   // [10][4]
    float* out = (float*)d_out;               // [8192][30]
    (void)d_ws; (void)ws_size;                // workspace not needed

    fused_kernel<<<2048, 256, 0, stream>>>(w, x, out);
}